// Round 1
// baseline (350.552 us; speedup 1.0000x reference)
//
#include <hip/hip_runtime.h>
#include <cstdint>
#include <cstddef>

#define N_NODES 12288
#define IN_F 256
#define OUT_F 128
#define KSPLIT 4
#define KC (N_NODES / KSPLIT)   /* 3072 */
#define NSTEP (KC / 32)         /* 96 */

using short8 = __attribute__((ext_vector_type(8))) short;
using f32x4  = __attribute__((ext_vector_type(4))) float;

__device__ inline unsigned int cvt_pk_bf16(float lo, float hi) {
  unsigned int r;
  asm volatile("v_cvt_pk_bf16_f32 %0, %1, %2" : "=v"(r) : "v"(lo), "v"(hi));
  return r;
}

__device__ inline unsigned short f2bf(float f) {
  unsigned int u = __float_as_uint(f);
  u = (u + 0x7FFFu + ((u >> 16) & 1u)) >> 16;
  return (unsigned short)u;
}

// ---------------------------------------------------------------- deg pass
// dinv[i] = rsqrt(1 + sum_j adj[i][j]); one block per row, coalesced float4.
__global__ __launch_bounds__(256) void k_deg(const float* __restrict__ adj,
                                             float* __restrict__ dinv) {
  const size_t row = blockIdx.x;
  const float4* p = reinterpret_cast<const float4*>(adj + row * N_NODES) + threadIdx.x;
  float s = 0.f;
#pragma unroll
  for (int i = 0; i < (N_NODES / 4) / 256; ++i) {
    float4 v = p[(size_t)i * 256];
    s += (v.x + v.y) + (v.z + v.w);
  }
#pragma unroll
  for (int off = 32; off >= 1; off >>= 1) s += __shfl_down(s, off, 64);
  __shared__ float red[4];
  const int lane = threadIdx.x & 63, w = threadIdx.x >> 6;
  if (lane == 0) red[w] = s;
  __syncthreads();
  if (threadIdx.x == 0) {
    float tot = (red[0] + red[1]) + (red[2] + red[3]) + 1.0f;
    dinv[row] = rsqrtf(tot);
  }
}

// ------------------------------------------------------------- support pass
// ssc[j][o] = dinv[j] * (x @ W)[j][o]  (fp32, row-major)
// sT[o][j]  = bf16(ssc[j][o])          (transposed, for contiguous B frags)
__global__ __launch_bounds__(256) void k_support(const float* __restrict__ x,
                                                 const float* __restrict__ W,
                                                 const float* __restrict__ dinv,
                                                 float* __restrict__ ssc,
                                                 unsigned short* __restrict__ sT) {
  const int r = threadIdx.x >> 5;            // 0..7
  const int c4 = (threadIdx.x & 31) << 2;    // 0..124
  const size_t row = (size_t)blockIdx.x * 8 + r;
  const float* xr = x + row * IN_F;
  float a0 = 0.f, a1 = 0.f, a2 = 0.f, a3 = 0.f;
#pragma unroll 4
  for (int k = 0; k < IN_F; ++k) {
    float xv = xr[k];
    float4 wv = *reinterpret_cast<const float4*>(W + (size_t)k * OUT_F + c4);
    a0 = fmaf(xv, wv.x, a0); a1 = fmaf(xv, wv.y, a1);
    a2 = fmaf(xv, wv.z, a2); a3 = fmaf(xv, wv.w, a3);
  }
  const float d = dinv[row];
  a0 *= d; a1 *= d; a2 *= d; a3 *= d;
  *reinterpret_cast<float4*>(ssc + row * OUT_F + c4) = make_float4(a0, a1, a2, a3);
  sT[(size_t)(c4 + 0) * N_NODES + row] = f2bf(a0);
  sT[(size_t)(c4 + 1) * N_NODES + row] = f2bf(a1);
  sT[(size_t)(c4 + 2) * N_NODES + row] = f2bf(a2);
  sT[(size_t)(c4 + 3) * N_NODES + row] = f2bf(a3);
}

// ----------------------------------------------------------------- big GEMM
// part[kc][i][o] = sum_{j in K-chunk kc} adj[i][j] * sT[o][j]
// Mtile=64 rows/block, full N=128, K split 4-way -> grid (192,4) = 768 blocks.
__global__ __launch_bounds__(256) void k_gemm(const float* __restrict__ adj,
                                              const unsigned short* __restrict__ sT,
                                              float* __restrict__ part) {
  __shared__ float As[2][64 * 32];            // 2 x 8 KB, fp32, XOR-swizzled chunks
  __shared__ unsigned short Bs[2][128 * 40];  // 2 x 10 KB, [col][k] padded to 40

  const int tid = threadIdx.x;
  const int lane = tid & 63;
  const int wv = tid >> 6;
  const size_t rowbase = (size_t)blockIdx.x * 64;
  const int kbase = blockIdx.y * KC;

  // A staging: thread t -> (row = t/8, kquad = t%8), source kquad XOR-swizzled
  // by row&7 so the (linear-dest) global_load_lds yields a bank-friendly layout.
  const int arow = tid >> 3;   // 0..31
  const int akq = tid & 7;
  const float* aseg0 = adj + (rowbase + arow) * (size_t)N_NODES + kbase +
                       ((akq ^ (arow & 7)) << 2);
  const float* aseg1 = aseg0 + (size_t)32 * N_NODES;

  // B staging: thread t -> col = t&127, half = t>>7 ; 32 B (16 bf16) each
  const int bcol = tid & 127;
  const int bhalf = tid >> 7;
  const unsigned short* bsrc = sT + (size_t)bcol * N_NODES + kbase + bhalf * 16;
  char* bdst0 = (char*)&Bs[0][0] + bcol * 80 + bhalf * 32;
  char* bdst1 = (char*)&Bs[1][0] + bcol * 80 + bhalf * 32;

  f32x4 acc[8];
#pragma unroll
  for (int i = 0; i < 8; ++i) acc[i] = (f32x4){0.f, 0.f, 0.f, 0.f};

  auto stageA = [&](int s, int buf) {
    char* dst = (char*)&As[buf][0] + tid * 16;
    __builtin_amdgcn_global_load_lds(
        (__attribute__((address_space(1))) void*)(aseg0 + s * 32),
        (__attribute__((address_space(3))) void*)dst, 16, 0, 0);
    __builtin_amdgcn_global_load_lds(
        (__attribute__((address_space(1))) void*)(aseg1 + s * 32),
        (__attribute__((address_space(3))) void*)(dst + 4096), 16, 0, 0);
  };
  auto loadB = [&](int s, float4& v0, float4& v1) {
    const char* p = (const char*)(bsrc + s * 32);
    v0 = *(const float4*)p;
    v1 = *(const float4*)(p + 16);
  };
  auto writeB = [&](int buf, float4 v0, float4 v1) {
    char* d = buf ? bdst1 : bdst0;
    *(float4*)d = v0;
    *(float4*)(d + 16) = v1;
  };
  auto compute = [&](int buf) {
    const char* Ab = (const char*)&As[buf][0];
    const char* Bb = (const char*)&Bs[buf][0];
    const int ar = (wv << 4) + (lane & 15);   // row in tile
    const int g = lane >> 4;                  // k-group
    const int abase = ar * 128;
    const int sw = (ar & 7) << 4;
    float4 alo = *(const float4*)(Ab + abase + ((g * 32) ^ sw));
    float4 ahi = *(const float4*)(Ab + abase + (((g * 32) + 16) ^ sw));
    union { unsigned int u[4]; short8 v; } af;
    af.u[0] = cvt_pk_bf16(alo.x, alo.y);
    af.u[1] = cvt_pk_bf16(alo.z, alo.w);
    af.u[2] = cvt_pk_bf16(ahi.x, ahi.y);
    af.u[3] = cvt_pk_bf16(ahi.z, ahi.w);
    const int boff = (lane & 15) * 80 + g * 16;
#pragma unroll
    for (int nt = 0; nt < 8; ++nt) {
      short8 bf = *(const short8*)(Bb + nt * (16 * 80) + boff);
      acc[nt] = __builtin_amdgcn_mfma_f32_16x16x32_bf16(af.v, bf, acc[nt], 0, 0, 0);
    }
  };

  { // prologue: stage step 0 into buf 0
    stageA(0, 0);
    float4 b0, b1; loadB(0, b0, b1);
    writeB(0, b0, b1);
  }
  __syncthreads();
  for (int s = 0; s < NSTEP; ++s) {
    const int buf = s & 1;
    float4 nb0, nb1;
    if (s + 1 < NSTEP) {
      stageA(s + 1, buf ^ 1);
      loadB(s + 1, nb0, nb1);
    }
    compute(buf);
    if (s + 1 < NSTEP) writeB(buf ^ 1, nb0, nb1);
    __syncthreads();
  }

  // epilogue: write fp32 partials (C/D layout: col=lane&15, row=(lane>>4)*4+r)
  float* pp = part + ((size_t)blockIdx.y * N_NODES + rowbase) * OUT_F;
  const int prow0 = (wv << 4) + ((lane >> 4) << 2);
  const int pcol = lane & 15;
#pragma unroll
  for (int nt = 0; nt < 8; ++nt) {
#pragma unroll
    for (int r = 0; r < 4; ++r) {
      pp[(size_t)(prow0 + r) * OUT_F + (nt << 4) + pcol] = acc[nt][r];
    }
  }
}

// ------------------------------------------------------------------- reduce
// out[i][o] = dinv[i] * (sum_kc part[kc][i][o] + ssc[i][o]) + b[o]
__global__ __launch_bounds__(256) void k_reduce(const float* __restrict__ part,
                                                const float* __restrict__ ssc,
                                                const float* __restrict__ dinv,
                                                const float* __restrict__ bias,
                                                float* __restrict__ out) {
  const size_t i4 = (size_t)blockIdx.x * 256 + threadIdx.x;  // float4 index
  const size_t row = i4 >> 5;                                // /32
  const int c4 = (int)(i4 & 31) << 2;
  const size_t off = i4 << 2;
  const size_t stride = (size_t)N_NODES * OUT_F;
  float4 p0 = *(const float4*)(part + off);
  float4 p1 = *(const float4*)(part + stride + off);
  float4 p2 = *(const float4*)(part + 2 * stride + off);
  float4 p3 = *(const float4*)(part + 3 * stride + off);
  float4 sc = *(const float4*)(ssc + off);
  float4 bv = *(const float4*)(bias + c4);
  const float d = dinv[row];
  float4 o;
  o.x = fmaf(d, (p0.x + p1.x) + (p2.x + p3.x) + sc.x, bv.x);
  o.y = fmaf(d, (p0.y + p1.y) + (p2.y + p3.y) + sc.y, bv.y);
  o.z = fmaf(d, (p0.z + p1.z) + (p2.z + p3.z) + sc.z, bv.z);
  o.w = fmaf(d, (p0.w + p1.w) + (p2.w + p3.w) + sc.w, bv.w);
  *reinterpret_cast<float4*>(out + off) = o;
}

extern "C" void kernel_launch(void* const* d_in, const int* in_sizes, int n_in,
                              void* d_out, int out_size, void* d_ws, size_t ws_size,
                              hipStream_t stream) {
  const float* x   = (const float*)d_in[0];
  const float* adj = (const float*)d_in[1];
  const float* W   = (const float*)d_in[2];
  const float* b   = (const float*)d_in[3];
  float* out = (float*)d_out;

  // workspace layout (bytes): dinv 48K | ssc 6.0M | sT 3.0M | part 24M  (~34.7 MB)
  char* ws = (char*)d_ws;
  float* dinv          = (float*)ws;
  float* ssc           = (float*)(ws + 49152);
  unsigned short* sT   = (unsigned short*)(ws + 49152 + 6291456);
  float* part          = (float*)(ws + 49152 + 6291456 + 3145728);

  k_deg<<<N_NODES, 256, 0, stream>>>(adj, dinv);
  k_support<<<N_NODES / 8, 256, 0, stream>>>(x, W, dinv, ssc, sT);
  k_gemm<<<dim3(N_NODES / 64, KSPLIT), 256, 0, stream>>>(adj, sT, part);
  k_reduce<<<(N_NODES * OUT_F / 4) / 256, 256, 0, stream>>>(part, ssc, dinv, b, out);
}

// Round 2
// 347.250 us; speedup vs baseline: 1.0095x; 1.0095x over previous
//
#include <hip/hip_runtime.h>
#include <cstdint>
#include <cstddef>

#define N_NODES 12288
#define IN_F 256
#define OUT_F 128
#define BM 48
#define BK 64
#define NSTEPS (N_NODES / BK)   /* 192 */

using short8 = __attribute__((ext_vector_type(8))) short;
using f32x4  = __attribute__((ext_vector_type(4))) float;

__device__ inline unsigned int cvt_pk_bf16(float lo, float hi) {
  unsigned int r;
  asm volatile("v_cvt_pk_bf16_f32 %0, %1, %2" : "=v"(r) : "v"(lo), "v"(hi));
  return r;
}

__device__ inline unsigned short f2bf(float f) {
  unsigned int u = __float_as_uint(f);
  u = (u + 0x7FFFu + ((u >> 16) & 1u)) >> 16;
  return (unsigned short)u;
}

// ---------------------------------------------------------------- deg pass
// dinv[i] = rsqrt(1 + sum_j adj[i][j]); one block per row, coalesced float4.
__global__ __launch_bounds__(256) void k_deg(const float* __restrict__ adj,
                                             float* __restrict__ dinv) {
  const size_t row = blockIdx.x;
  const float4* p = reinterpret_cast<const float4*>(adj + row * N_NODES) + threadIdx.x;
  float s = 0.f;
#pragma unroll
  for (int i = 0; i < (N_NODES / 4) / 256; ++i) {
    float4 v = p[(size_t)i * 256];
    s += (v.x + v.y) + (v.z + v.w);
  }
#pragma unroll
  for (int off = 32; off >= 1; off >>= 1) s += __shfl_down(s, off, 64);
  __shared__ float red[4];
  const int lane = threadIdx.x & 63, w = threadIdx.x >> 6;
  if (lane == 0) red[w] = s;
  __syncthreads();
  if (threadIdx.x == 0) {
    float tot = (red[0] + red[1]) + (red[2] + red[3]) + 1.0f;
    dinv[row] = rsqrtf(tot);
  }
}

// ------------------------------------------------------------- support pass
// ssc[j][o] = dinv[j] * (x @ W)[j][o]  (fp32, row-major)
// sT[o][j]  = bf16(ssc[j][o])          (transposed, for contiguous B frags)
__global__ __launch_bounds__(256) void k_support(const float* __restrict__ x,
                                                 const float* __restrict__ W,
                                                 const float* __restrict__ dinv,
                                                 float* __restrict__ ssc,
                                                 unsigned short* __restrict__ sT) {
  const int r = threadIdx.x >> 5;            // 0..7
  const int c4 = (threadIdx.x & 31) << 2;    // 0..124
  const size_t row = (size_t)blockIdx.x * 8 + r;
  const float* xr = x + row * IN_F;
  float a0 = 0.f, a1 = 0.f, a2 = 0.f, a3 = 0.f;
#pragma unroll 4
  for (int k = 0; k < IN_F; ++k) {
    float xv = xr[k];
    float4 wv = *reinterpret_cast<const float4*>(W + (size_t)k * OUT_F + c4);
    a0 = fmaf(xv, wv.x, a0); a1 = fmaf(xv, wv.y, a1);
    a2 = fmaf(xv, wv.z, a2); a3 = fmaf(xv, wv.w, a3);
  }
  const float d = dinv[row];
  a0 *= d; a1 *= d; a2 *= d; a3 *= d;
  *reinterpret_cast<float4*>(ssc + row * OUT_F + c4) = make_float4(a0, a1, a2, a3);
  sT[(size_t)(c4 + 0) * N_NODES + row] = f2bf(a0);
  sT[(size_t)(c4 + 1) * N_NODES + row] = f2bf(a1);
  sT[(size_t)(c4 + 2) * N_NODES + row] = f2bf(a2);
  sT[(size_t)(c4 + 3) * N_NODES + row] = f2bf(a3);
}

// ----------------------------------------------------------------- big GEMM
// out[i][o] = dinv[i]*( sum_j adj[i][j]*sT[o][j] + ssc[i][o] ) + b[o]
// BM=48 rows/block, full N=128, full K -> grid 256 = 1 block/CU.
// A: 4-deep LDS ring, staged 2 steps ahead via global_load_lds (counted vmcnt).
// B: register prefetch 1 step ahead from L2-resident sT.
__global__ __launch_bounds__(256, 1) void k_gemm(const float* __restrict__ adj,
                                                 const unsigned short* __restrict__ sT,
                                                 const float* __restrict__ ssc,
                                                 const float* __restrict__ dinv,
                                                 const float* __restrict__ bias,
                                                 float* __restrict__ out) {
  __shared__ float As[4][BM * BK];   // 4 x 12 KB = 48 KB

  const int tid = threadIdx.x;
  const int lane = tid & 63;
  const int wv = tid >> 6;
  const size_t rowbase = (size_t)blockIdx.x * BM;

  // A staging map: thread t -> row16 r0 = t>>4 (rows r0, r0+16, r0+32),
  // 16B chunk q = t&15, source chunk XOR-swizzled by r0 (linear LDS dest).
  const int r0 = tid >> 4;
  const int q = tid & 15;
  const float* asrc = adj + (rowbase + r0) * (size_t)N_NODES + ((q ^ r0) << 2);

  // B frag map: lane -> col c15 = lane&15 (+nt*16), k-group g = lane>>4.
  const int g = lane >> 4;
  const int c15 = lane & 15;
  const unsigned short* bptr = sT + (size_t)(wv * 32 + c15) * N_NODES + g * 8;

  f32x4 acc[3][2];
#pragma unroll
  for (int mt = 0; mt < 3; ++mt)
#pragma unroll
    for (int nt = 0; nt < 2; ++nt) acc[mt][nt] = (f32x4){0.f, 0.f, 0.f, 0.f};

  short8 bA[2][2], bB[2][2];  // [nt][kt], ping-pong sets

  auto stageA = [&](int s) {
    char* base = (char*)&As[s & 3][0] + tid * 16;
    const float* sp = asrc + (size_t)s * BK;
#pragma unroll
    for (int j = 0; j < 3; ++j) {
      __builtin_amdgcn_global_load_lds(
          (__attribute__((address_space(1))) void*)(sp + (size_t)j * 16 * N_NODES),
          (__attribute__((address_space(3))) void*)(base + j * 4096), 16, 0, 0);
    }
  };
  auto loadB = [&](int s, short8 (&B)[2][2]) {
#pragma unroll
    for (int nt = 0; nt < 2; ++nt)
#pragma unroll
      for (int kt = 0; kt < 2; ++kt)
        B[nt][kt] = *(const short8*)(bptr + (size_t)nt * 16 * N_NODES +
                                     (size_t)s * BK + kt * 32);
  };
  auto compute = [&](int s, short8 (&B)[2][2]) {
    const char* Ab = (const char*)&As[s & 3][0];
#pragma unroll
    for (int mt = 0; mt < 3; ++mt) {
      short8 af[2];
#pragma unroll
      for (int kt = 0; kt < 2; ++kt) {
        const int cbase = kt * 8 + g * 2;
        const int rowoff = mt * 4096 + c15 * 256;
        f32x4 lo = *(const f32x4*)(Ab + rowoff + ((cbase ^ c15) << 4));
        f32x4 hi = *(const f32x4*)(Ab + rowoff + (((cbase + 1) ^ c15) << 4));
        union { unsigned int u[4]; short8 v; } t;
        t.u[0] = cvt_pk_bf16(lo[0], lo[1]);
        t.u[1] = cvt_pk_bf16(lo[2], lo[3]);
        t.u[2] = cvt_pk_bf16(hi[0], hi[1]);
        t.u[3] = cvt_pk_bf16(hi[2], hi[3]);
        af[kt] = t.v;
      }
#pragma unroll
      for (int nt = 0; nt < 2; ++nt)
#pragma unroll
        for (int kt = 0; kt < 2; ++kt)
          acc[mt][nt] = __builtin_amdgcn_mfma_f32_16x16x32_bf16(
              af[kt], B[nt][kt], acc[mt][nt], 0, 0, 0);
    }
  };

// One pipeline step. Issue order pinned (B loads, then A stages) so the
// counted vmcnt is valid: in steady state, ops newer than B(s) =
// A(s+1)[3] + B(s+1)[4] + A(s+2)[3] = 10.
#define GSTEP(s, CUR, NXT, DOSTAGE, DOLOADB, VMC)                \
  {                                                              \
    if (DOLOADB) loadB((s) + 1, NXT);                            \
    __builtin_amdgcn_sched_barrier(0);                           \
    if (DOSTAGE) stageA((s) + 2);                                \
    asm volatile("s_waitcnt vmcnt(" VMC ")" ::: "memory");       \
    __builtin_amdgcn_s_barrier();                                \
    compute((s), CUR);                                           \
  }

  // prologue: A(0), B(0), A(1)  (order matters for the count)
  stageA(0);
  __builtin_amdgcn_sched_barrier(0);
  loadB(0, bA);
  __builtin_amdgcn_sched_barrier(0);
  stageA(1);

  for (int s = 0; s < NSTEPS - 2; s += 2) {
    GSTEP(s, bA, bB, 1, 1, "10");
    GSTEP(s + 1, bB, bA, 1, 1, "10");
  }
  // tails: s=190 (no stage; after B(190): A(191)[3]+B(191)[4] = 7), s=191
  GSTEP(NSTEPS - 2, bA, bB, 0, 1, "7");
  GSTEP(NSTEPS - 1, bB, bA, 0, 0, "0");
#undef GSTEP

  // epilogue: C/D layout col=lane&15, row=(lane>>4)*4+r
  const int col0 = wv * 32 + c15;
#pragma unroll
  for (int mt = 0; mt < 3; ++mt) {
#pragma unroll
    for (int nt = 0; nt < 2; ++nt) {
      const int col = col0 + nt * 16;
      const float bv = bias[col];
#pragma unroll
      for (int r = 0; r < 4; ++r) {
        const size_t orow = rowbase + mt * 16 + (g << 2) + r;
        const float d = dinv[orow];
        out[orow * OUT_F + col] =
            fmaf(d, acc[mt][nt][r] + ssc[orow * OUT_F + col], bv);
      }
    }
  }
}

extern "C" void kernel_launch(void* const* d_in, const int* in_sizes, int n_in,
                              void* d_out, int out_size, void* d_ws, size_t ws_size,
                              hipStream_t stream) {
  const float* x   = (const float*)d_in[0];
  const float* adj = (const float*)d_in[1];
  const float* W   = (const float*)d_in[2];
  const float* b   = (const float*)d_in[3];
  float* out = (float*)d_out;

  // workspace layout (bytes): dinv 48K | ssc 6.0M | sT 3.0M  (~9.5 MB)
  char* ws = (char*)d_ws;
  float* dinv        = (float*)ws;
  float* ssc         = (float*)(ws + 49152);
  unsigned short* sT = (unsigned short*)(ws + 49152 + 6291456);

  k_deg<<<N_NODES, 256, 0, stream>>>(adj, dinv);
  k_support<<<N_NODES / 8, 256, 0, stream>>>(x, W, dinv, ssc, sT);
  k_gemm<<<256, 256, 0, stream>>>(adj, sT, ssc, dinv, b, out);
}